// Round 6
// baseline (368.559 us; speedup 1.0000x reference)
//
#include <hip/hip_runtime.h>

#define LRELU(x) ((x) > 0.f ? (x) : 0.2f * (x))

typedef __attribute__((ext_vector_type(8))) short bf16x8;
typedef __attribute__((ext_vector_type(4))) float f32x4;

__device__ __forceinline__ unsigned short f2bf(float f) {
  unsigned int u = __float_as_uint(f);
  unsigned int r = (u + 0x7fffu + ((u >> 16) & 1u)) >> 16;  // RNE
  return (unsigned short)r;
}
__device__ __forceinline__ float bf2f(unsigned short u) {
  return __uint_as_float(((unsigned int)u) << 16);
}
__device__ __forceinline__ float bflo(unsigned int u) { return __uint_as_float(u << 16); }
__device__ __forceinline__ float bfhi(unsigned int u) { return __uint_as_float(u & 0xffff0000u); }

__device__ __forceinline__ void wait_vm5() { asm volatile("s_waitcnt vmcnt(5)" ::: "memory"); }
__device__ __forceinline__ void wait_vm0() { asm volatile("s_waitcnt vmcnt(0)" ::: "memory"); }
__device__ __forceinline__ void lgkm0()   { asm volatile("s_waitcnt lgkmcnt(0)" ::: "memory"); }

#define GLOAD_LDS16(g, l)                                                  \
  __builtin_amdgcn_global_load_lds(                                        \
      (const __attribute__((address_space(1))) void*)(g),                  \
      (__attribute__((address_space(3))) void*)(l), 16, 0, 0)

// ---- edge dtype detection ----
__global__ void detect_i64_kernel(const int* __restrict__ w, int* __restrict__ flag) {
  if (threadIdx.x == 0 && blockIdx.x == 0) {
    int all0 = 1;
    for (int j = 0; j < 128; j++)
      if (w[2 * j + 1] != 0) { all0 = 0; break; }
    *flag = all0;
  }
}
__device__ __forceinline__ int edge_at(const void* ei, long long idx, int is64) {
  if (is64) return (int)((const long long*)ei)[idx];
  return ((const int*)ei)[idx];
}

// ---- CSR build ----
__global__ void hist_kernel(const void* __restrict__ ei, const int* __restrict__ flag,
                            int* __restrict__ counts, int E, int N) {
  int i = blockIdx.x * blockDim.x + threadIdx.x;
  int tot = E + N;
  if (i >= tot) return;
  int f = *flag;
  int d = (i < E) ? edge_at(ei, (long long)E + i, f) : (i - E);
  atomicAdd(&counts[d], 1);
}

__global__ __launch_bounds__(512) void scan1_kernel(const int* __restrict__ counts,
                                                    int* __restrict__ partial,
                                                    int* __restrict__ blocksums, int N) {
  __shared__ int sm[1024];
  int t = threadIdx.x;
  int i = blockIdx.x * 512 + t;
  int v = (i < N) ? counts[i] : 0;
  int* cur = sm; int* nxt = sm + 512;
  cur[t] = v;
  __syncthreads();
  for (int off = 1; off < 512; off <<= 1) {
    int x = cur[t];
    if (t >= off) x += cur[t - off];
    nxt[t] = x;
    __syncthreads();
    int* tmp = cur; cur = nxt; nxt = tmp;
  }
  if (i < N) partial[i] = cur[t];
  if (t == 511) blocksums[blockIdx.x] = cur[511];
}

__global__ __launch_bounds__(512) void scan2_kernel(int* __restrict__ bs, int B) {
  __shared__ int sm[1024];
  int t = threadIdx.x;
  int v = (t < B) ? bs[t] : 0;
  int* cur = sm; int* nxt = sm + 512;
  cur[t] = v;
  __syncthreads();
  for (int off = 1; off < 512; off <<= 1) {
    int x = cur[t];
    if (t >= off) x += cur[t - off];
    nxt[t] = x;
    __syncthreads();
    int* tmp = cur; cur = nxt; nxt = tmp;
  }
  if (t < B) bs[t] = cur[t] - v;
}

__global__ void scan3_kernel(const int* __restrict__ partial, const int* __restrict__ bs,
                             int* __restrict__ row_ptr, int* __restrict__ cursor, int N) {
  int i = blockIdx.x * blockDim.x + threadIdx.x;
  if (i == 0) { row_ptr[0] = 0; cursor[0] = 0; }
  if (i < N) {
    int v = partial[i] + bs[i >> 9];
    row_ptr[i + 1] = v;
    if (i + 1 < N) cursor[i + 1] = v;
  }
}

__global__ void scatter_kernel(const void* __restrict__ ei, const int* __restrict__ flag,
                               int* __restrict__ cursor, int* __restrict__ srcs, int E, int N) {
  int i = blockIdx.x * blockDim.x + threadIdx.x;
  int tot = E + N;
  if (i >= tot) return;
  int f = *flag;
  int s, d;
  if (i < E) {
    s = edge_at(ei, i, f);
    d = edge_at(ei, (long long)E + i, f);
  } else {
    s = i - E; d = s;
  }
  int pos = atomicAdd(&cursor[d], 1);
  srcs[pos] = s;
}

// ---- prep: fp32 -> bf16 (hi only) ----
__global__ __launch_bounds__(256) void tobf16_kernel(const float* __restrict__ x,
                                                     unsigned short* __restrict__ xh, int n4) {
  int i = blockIdx.x * 256 + threadIdx.x;
  if (i >= n4) return;
  float4 v = ((const float4*)x)[i];
  ushort4 h;
  h.x = f2bf(v.x); h.y = f2bf(v.y); h.z = f2bf(v.z); h.w = f2bf(v.w);
  ((ushort4*)xh)[i] = h;
}

// ---- prep: transpose + split W [K][Nc] -> Wt_h/Wt_l [Nc][K] ----
__global__ __launch_bounds__(256) void wprep_kernel(const float* __restrict__ W,
                                                    unsigned short* __restrict__ Wth,
                                                    unsigned short* __restrict__ Wtl,
                                                    int K, int Nc) {
  int idx = blockIdx.x * 256 + threadIdx.x;
  if (idx >= K * Nc) return;
  int n = idx / K, k = idx - n * K;
  float v = W[(size_t)k * Nc + n];
  unsigned short h = f2bf(v);
  Wth[idx] = h;
  Wtl[idx] = f2bf(v - bf2f(h));
}

// ---- MFMA GEMM, 2 segments (A@B0 + A@B1), global_load_lds + dbuf + counted vmcnt ----
template <int BROWS, int BCOLS, int WALONG_N, int H>
__global__ __launch_bounds__(256) void gemm_mfma(
    const unsigned short* __restrict__ A0, const unsigned short* __restrict__ B0,
    const unsigned short* __restrict__ B1, int M, int Ka,
    unsigned short* __restrict__ Cb, const float* __restrict__ asrc,
    const float* __restrict__ adst, float* __restrict__ as, float* __restrict__ ad) {
  __shared__ __align__(16) unsigned short Asm[2][4][BROWS][8];
  __shared__ __align__(16) unsigned short Bsm[2][4][BCOLS][8];
  int tid = threadIdx.x;
  int w = tid >> 6, l = tid & 63;
  int l16 = l & 15, lg = l >> 4;
  int rowbase = blockIdx.y * BROWS;
  int wrow = WALONG_N ? 0 : w * 64;
  int wcol = WALONG_N ? w * 64 : 0;
  const int KS = Ka / 32;
  const int NST = 2 * KS;
  const int CH_A = BROWS * 4 / 256;
  const int CH_B = BCOLS * 4 / 256;

  auto stage = [&](int buf, int s) {
    int seg = s / KS;
    int kk = (s - seg * KS) * 32;
    const unsigned short* Bp = seg ? B1 : B0;
#pragma unroll
    for (int q = 0; q < CH_A; ++q) {
      int i = q * 256 + tid;
      int p = i / BROWS, r = i % BROWS;
      int gr = rowbase + r;
      if (gr >= M) gr = M - 1;
      const unsigned short* src = A0 + (size_t)gr * Ka + kk + p * 8;
      unsigned short* dst = &Asm[buf][0][0][0] + ((size_t)q * 256 + (tid & ~63)) * 8;
      GLOAD_LDS16(src, dst);
    }
#pragma unroll
    for (int q = 0; q < CH_B; ++q) {
      int i = q * 256 + tid;
      int p = i / BCOLS, r = i % BCOLS;
      const unsigned short* src = Bp + (size_t)r * Ka + kk + p * 8;
      unsigned short* dst = &Bsm[buf][0][0][0] + ((size_t)q * 256 + (tid & ~63)) * 8;
      GLOAD_LDS16(src, dst);
    }
  };

  f32x4 acc[4][4] = {};
  stage(0, 0);
  int buf = 0;
  for (int s = 0; s < NST; ++s) {
    if (s + 1 < NST) { stage(buf ^ 1, s + 1); wait_vm5(); }
    else             { wait_vm0(); }
    __builtin_amdgcn_s_barrier();
    bf16x8 af[4], bfr[4];
#pragma unroll
    for (int m = 0; m < 4; ++m) af[m] = *(const bf16x8*)&Asm[buf][lg][wrow + m * 16 + l16][0];
#pragma unroll
    for (int n = 0; n < 4; ++n) bfr[n] = *(const bf16x8*)&Bsm[buf][lg][wcol + n * 16 + l16][0];
#pragma unroll
    for (int m = 0; m < 4; ++m)
#pragma unroll
      for (int n = 0; n < 4; ++n)
        acc[m][n] = __builtin_amdgcn_mfma_f32_16x16x32_bf16(af[m], bfr[n], acc[m][n], 0, 0, 0);
    __builtin_amdgcn_s_barrier();
    buf ^= 1;
  }
#pragma unroll
  for (int m = 0; m < 4; ++m) {
    int r = rowbase + wrow + m * 16 + lg * 4;
#pragma unroll
    for (int n = 0; n < 4; ++n) {
      int c = wcol + n * 16 + l16;
#pragma unroll
      for (int j = 0; j < 4; ++j) {
        if (r + j < M) Cb[(size_t)(r + j) * BCOLS + c] = f2bf(acc[m][n][j]);
      }
    }
  }
  float asv[4], adv_[4];
#pragma unroll
  for (int n = 0; n < 4; ++n) {
    int c = wcol + n * 16 + l16;
    asv[n] = asrc[c];
    adv_[n] = adst[c];
  }
  int head = WALONG_N ? w : 0;
#pragma unroll
  for (int m = 0; m < 4; ++m) {
#pragma unroll
    for (int j = 0; j < 4; ++j) {
      float ps = 0.f, pd = 0.f;
#pragma unroll
      for (int n = 0; n < 4; ++n) {
        ps = fmaf(acc[m][n][j], asv[n], ps);
        pd = fmaf(acc[m][n][j], adv_[n], pd);
      }
#pragma unroll
      for (int o = 1; o < 16; o <<= 1) { ps += __shfl_xor(ps, o); pd += __shfl_xor(pd, o); }
      int r = rowbase + wrow + m * 16 + lg * 4 + j;
      if (l16 == 0 && r < M) {
        as[(size_t)r * H + head] = ps;
        ad[(size_t)r * H + head] = pd;
      }
    }
  }
}

// ---- layer-2 "GEMM" as per-node matvec: wave per node, W2 fp32 resident in LDS ----
// h2[n][c2] = sum_c o1[n][c]*W2[c][c2]; fused as2/ad2 alpha dots. ROUNDS nodes per wave.
__global__ __launch_bounds__(256) void gemm2_node(const unsigned short* __restrict__ o1h,
                                                  const float* __restrict__ W2,
                                                  const float* __restrict__ asrc2,
                                                  const float* __restrict__ adst2,
                                                  unsigned short* __restrict__ h2b,
                                                  float* __restrict__ as2,
                                                  float* __restrict__ ad2,
                                                  int N, int rounds) {
  __shared__ float w2s[256][64];    // 64KB, staged once
  __shared__ float rowbuf[4][256];  // 4KB, per-wave row broadcast
  int tid = threadIdx.x;
  int w = tid >> 6, l = tid & 63;
  // stage W2 (16384 floats = 4096 float4)
  const float4* W4 = (const float4*)W2;
  float4* w4s = (float4*)&w2s[0][0];
  for (int i = tid; i < 4096; i += 256) w4s[i] = W4[i];
  __syncthreads();
  float av = asrc2[l], dv = adst2[l];
  int base = blockIdx.x * 4 * rounds;
  for (int r = 0; r < rounds; ++r) {
    int gw = base + r * 4 + w;
    if (gw >= N) gw = N - 1;  // benign duplicate
    ushort4 rv = *(const ushort4*)(o1h + (size_t)gw * 256 + 4 * l);
    *(float4*)&rowbuf[w][4 * l] =
        make_float4(bf2f(rv.x), bf2f(rv.y), bf2f(rv.z), bf2f(rv.w));
    lgkm0();  // wave-local visibility (rowbuf is wave-private)
    float acc = 0.f;
#pragma unroll 4
    for (int c = 0; c < 256; ++c) acc = fmaf(rowbuf[w][c], w2s[c][l], acc);
    h2b[(size_t)gw * 64 + l] = f2bf(acc);
    float ps = acc * av, pd = acc * dv;
#pragma unroll
    for (int o = 32; o; o >>= 1) { ps += __shfl_xor(ps, o); pd += __shfl_xor(pd, o); }
    if (l == 0) { as2[gw] = ps; ad2[gw] = pd; }
  }
}

// ---- layer-1 aggregation: wave per node; lane=(g,p): edge-offset g, 16 channels p ----
__global__ __launch_bounds__(256) void agg4(const unsigned short* __restrict__ hb,
                                            const float* __restrict__ as,
                                            const float* __restrict__ ad,
                                            const int* __restrict__ row_ptr,
                                            const int* __restrict__ srcs,
                                            const float* __restrict__ bias,
                                            unsigned short* __restrict__ oh, int N) {
  __shared__ float els[4][128][4];
  int tid = threadIdx.x;
  int w = tid >> 6, l = tid & 63;
  int gw = (blockIdx.x << 2) + w;
  if (gw >= N) gw = N - 1;
  int g = l >> 4, p = l & 15;
  int beg = row_ptr[gw], end = row_ptr[gw + 1];
  float4 adv = *(const float4*)(ad + (size_t)gw * 4);
  float m0 = -1e30f, m1 = -1e30f, m2 = -1e30f, m3 = -1e30f;
  for (int j = beg + l; j < end; j += 64) {
    int sn = srcs[j];
    float4 a = *(const float4*)(as + (size_t)sn * 4);
    float e0 = LRELU(a.x + adv.x), e1 = LRELU(a.y + adv.y);
    float e2 = LRELU(a.z + adv.z), e3 = LRELU(a.w + adv.w);
    int slot = j - beg;
    if (slot < 128) {
      els[w][slot][0] = e0; els[w][slot][1] = e1;
      els[w][slot][2] = e2; els[w][slot][3] = e3;
    }
    m0 = fmaxf(m0, e0); m1 = fmaxf(m1, e1);
    m2 = fmaxf(m2, e2); m3 = fmaxf(m3, e3);
  }
#pragma unroll
  for (int o = 32; o; o >>= 1) {
    m0 = fmaxf(m0, __shfl_xor(m0, o));
    m1 = fmaxf(m1, __shfl_xor(m1, o));
    m2 = fmaxf(m2, __shfl_xor(m2, o));
    m3 = fmaxf(m3, __shfl_xor(m3, o));
  }
  lgkm0();
  float s0 = 0.f, s1 = 0.f, s2 = 0.f, s3 = 0.f;
  for (int j = beg + l; j < end; j += 64) {
    int slot = j - beg;
    float e0, e1, e2, e3;
    if (slot < 128) {
      e0 = els[w][slot][0]; e1 = els[w][slot][1];
      e2 = els[w][slot][2]; e3 = els[w][slot][3];
    } else {
      int sn = srcs[j];
      float4 a = *(const float4*)(as + (size_t)sn * 4);
      e0 = LRELU(a.x + adv.x); e1 = LRELU(a.y + adv.y);
      e2 = LRELU(a.z + adv.z); e3 = LRELU(a.w + adv.w);
    }
    s0 += __expf(e0 - m0); s1 += __expf(e1 - m1);
    s2 += __expf(e2 - m2); s3 += __expf(e3 - m3);
  }
#pragma unroll
  for (int o = 32; o; o >>= 1) {
    s0 += __shfl_xor(s0, o); s1 += __shfl_xor(s1, o);
    s2 += __shfl_xor(s2, o); s3 += __shfl_xor(s3, o);
  }
  float i0 = 1.f / (s0 + 1e-16f), i1 = 1.f / (s1 + 1e-16f);
  float i2 = 1.f / (s2 + 1e-16f), i3 = 1.f / (s3 + 1e-16f);
  int head = p >> 2;
  float Mh   = head == 0 ? m0 : head == 1 ? m1 : head == 2 ? m2 : m3;
  float Ih   = head == 0 ? i0 : head == 1 ? i1 : head == 2 ? i2 : i3;
  float advh = head == 0 ? adv.x : head == 1 ? adv.y : head == 2 ? adv.z : adv.w;
  float acc[16] = {};
  for (int j0 = beg; j0 < end; j0 += 4) {
    int j = j0 + g;
    if (j < end) {
      int sn = srcs[j];
      int slot = j - beg;
      float e;
      if (slot < 128) {
        e = els[w][slot][head];
      } else {
        float4 a = *(const float4*)(as + (size_t)sn * 4);
        float ah = head == 0 ? a.x : head == 1 ? a.y : head == 2 ? a.z : a.w;
        e = LRELU(ah + advh);
      }
      float al = __expf(e - Mh) * Ih;
      const unsigned short* hp = hb + (size_t)sn * 256 + p * 16;
      uint4 v0 = *(const uint4*)(hp);
      uint4 v1 = *(const uint4*)(hp + 8);
      acc[0]  = fmaf(al, bflo(v0.x), acc[0]);  acc[1]  = fmaf(al, bfhi(v0.x), acc[1]);
      acc[2]  = fmaf(al, bflo(v0.y), acc[2]);  acc[3]  = fmaf(al, bfhi(v0.y), acc[3]);
      acc[4]  = fmaf(al, bflo(v0.z), acc[4]);  acc[5]  = fmaf(al, bfhi(v0.z), acc[5]);
      acc[6]  = fmaf(al, bflo(v0.w), acc[6]);  acc[7]  = fmaf(al, bfhi(v0.w), acc[7]);
      acc[8]  = fmaf(al, bflo(v1.x), acc[8]);  acc[9]  = fmaf(al, bfhi(v1.x), acc[9]);
      acc[10] = fmaf(al, bflo(v1.y), acc[10]); acc[11] = fmaf(al, bfhi(v1.y), acc[11]);
      acc[12] = fmaf(al, bflo(v1.z), acc[12]); acc[13] = fmaf(al, bfhi(v1.z), acc[13]);
      acc[14] = fmaf(al, bflo(v1.w), acc[14]); acc[15] = fmaf(al, bfhi(v1.w), acc[15]);
    }
  }
#pragma unroll
  for (int i = 0; i < 16; ++i) acc[i] += __shfl_xor(acc[i], 16);
#pragma unroll
  for (int i = 0; i < 16; ++i) acc[i] += __shfl_xor(acc[i], 32);
  float o0 = g == 0 ? acc[0] : g == 1 ? acc[4]  : g == 2 ? acc[8]  : acc[12];
  float o1 = g == 0 ? acc[1] : g == 1 ? acc[5]  : g == 2 ? acc[9]  : acc[13];
  float o2 = g == 0 ? acc[2] : g == 1 ? acc[6]  : g == 2 ? acc[10] : acc[14];
  float o3 = g == 0 ? acc[3] : g == 1 ? acc[7]  : g == 2 ? acc[11] : acc[15];
  int c = p * 16 + g * 4;
  ushort4 ov;
  ov.x = f2bf(fmaxf(o0 + bias[c + 0], 0.f));
  ov.y = f2bf(fmaxf(o1 + bias[c + 1], 0.f));
  ov.z = f2bf(fmaxf(o2 + bias[c + 2], 0.f));
  ov.w = f2bf(fmaxf(o3 + bias[c + 3], 0.f));
  *(ushort4*)(oh + (size_t)gw * 256 + c) = ov;
}

// ---- layer-2 aggregation: wave per node; lane=(g,p): edge g, 4 channels p ----
__global__ __launch_bounds__(256) void agg1(const unsigned short* __restrict__ hb,
                                            const float* __restrict__ as,
                                            const float* __restrict__ ad,
                                            const int* __restrict__ row_ptr,
                                            const int* __restrict__ srcs,
                                            const float* __restrict__ bias,
                                            float* __restrict__ out, int N) {
  __shared__ float els[4][128];
  int tid = threadIdx.x;
  int w = tid >> 6, l = tid & 63;
  int gw = (blockIdx.x << 2) + w;
  if (gw >= N) gw = N - 1;
  int g = l >> 4, p = l & 15;
  int beg = row_ptr[gw], end = row_ptr[gw + 1];
  float adn = ad[gw];
  float m = -1e30f;
  for (int j = beg + l; j < end; j += 64) {
    float e = LRELU(as[srcs[j]] + adn);
    int slot = j - beg;
    if (slot < 128) els[w][slot] = e;
    m = fmaxf(m, e);
  }
#pragma unroll
  for (int o = 32; o; o >>= 1) m = fmaxf(m, __shfl_xor(m, o));
  lgkm0();
  float s = 0.f;
  for (int j = beg + l; j < end; j += 64) {
    int slot = j - beg;
    float e = (slot < 128) ? els[w][slot] : LRELU(as[srcs[j]] + adn);
    s += __expf(e - m);
  }
#pragma unroll
  for (int o = 32; o; o >>= 1) s += __shfl_xor(s, o);
  float inv = 1.f / (s + 1e-16f);
  float acc[4] = {};
  for (int j0 = beg; j0 < end; j0 += 4) {
    int j = j0 + g;
    if (j < end) {
      int sn = srcs[j];
      int slot = j - beg;
      float e = (slot < 128) ? els[w][slot] : LRELU(as[sn] + adn);
      float al = __expf(e - m) * inv;
      ushort4 hv = *(const ushort4*)(hb + (size_t)sn * 64 + p * 4);
      acc[0] = fmaf(al, bf2f(hv.x), acc[0]);
      acc[1] = fmaf(al, bf2f(hv.y), acc[1]);
      acc[2] = fmaf(al, bf2f(hv.z), acc[2]);
      acc[3] = fmaf(al, bf2f(hv.w), acc[3]);
    }
  }
#pragma unroll
  for (int i = 0; i < 4; ++i) acc[i] += __shfl_xor(acc[i], 16);
#pragma unroll
  for (int i = 0; i < 4; ++i) acc[i] += __shfl_xor(acc[i], 32);
  float ov = g == 0 ? acc[0] : g == 1 ? acc[1] : g == 2 ? acc[2] : acc[3];
  int c = p * 4 + g;
  out[(size_t)gw * 64 + c] = ov + bias[c];
}

extern "C" void kernel_launch(void* const* d_in, const int* in_sizes, int n_in,
                              void* d_out, int out_size, void* d_ws, size_t ws_size,
                              hipStream_t stream) {
  const float* x      = (const float*)d_in[0];
  const void*  ei     = d_in[1];
  const float* W1     = (const float*)d_in[2];
  const float* a_src1 = (const float*)d_in[3];
  const float* a_dst1 = (const float*)d_in[4];
  const float* b1     = (const float*)d_in[5];
  const float* W2     = (const float*)d_in[6];
  const float* a_src2 = (const float*)d_in[7];
  const float* a_dst2 = (const float*)d_in[8];
  const float* b2     = (const float*)d_in[9];

  const int Fin = 128;
  const int N   = in_sizes[0] / Fin;  // 50000
  const int E   = in_sizes[1] / 2;    // 800000
  const int HC1 = in_sizes[2] / Fin;  // 256
  const int Etot = E + N;

  char* wp = (char*)d_ws;
  auto alloc = [&](size_t bytes) {
    void* p = (void*)wp;
    wp += (bytes + 255) & ~(size_t)255;
    return p;
  };
  int* counts    = (int*)alloc((size_t)N * 4);
  int* row_ptr   = (int*)alloc((size_t)(N + 1) * 4);
  int* cursor    = (int*)alloc((size_t)N * 4);
  int* partial   = (int*)alloc((size_t)N * 4);
  int* blocksums = (int*)alloc(4096);
  int* flag      = (int*)alloc(256);
  int* srcs      = (int*)alloc((size_t)Etot * 4);
  unsigned short* xh   = (unsigned short*)alloc((size_t)N * Fin * 2);   // 12.8MB
  unsigned short* xpad = (unsigned short*)alloc((size_t)N * Fin * 2);   // o1h tail region
  unsigned short* W1th = (unsigned short*)alloc((size_t)HC1 * Fin * 2);
  unsigned short* W1tl = (unsigned short*)alloc((size_t)HC1 * Fin * 2);
  unsigned short* h1b  = (unsigned short*)alloc((size_t)N * 256 * 2);   // 25.6MB
  float* as1 = (float*)alloc((size_t)N * 4 * 4);
  float* ad1 = (float*)alloc((size_t)N * 4 * 4);
  float* as2 = (float*)alloc((size_t)N * 4);
  float* ad2 = (float*)alloc((size_t)N * 4);
  (void)xpad;
  // aliases (disjoint lifetimes):
  unsigned short* o1h = xh;   // xh dead after gemm1; xh+xpad = 25.6MB contiguous
  unsigned short* h2b = h1b;  // h1b dead after agg4

  const int SB = (N + 511) / 512;

  // ---- CSR build ----
  detect_i64_kernel<<<1, 64, 0, stream>>>((const int*)ei, flag);
  hipMemsetAsync(counts, 0, (size_t)N * 4, stream);
  hist_kernel<<<(Etot + 255) / 256, 256, 0, stream>>>(ei, flag, counts, E, N);
  scan1_kernel<<<SB, 512, 0, stream>>>(counts, partial, blocksums, N);
  scan2_kernel<<<1, 512, 0, stream>>>(blocksums, SB);
  scan3_kernel<<<(N + 255) / 256, 256, 0, stream>>>(partial, blocksums, row_ptr, cursor, N);
  scatter_kernel<<<(Etot + 255) / 256, 256, 0, stream>>>(ei, flag, cursor, srcs, E, N);

  // ---- prep ----
  int n4 = N * Fin / 4;
  tobf16_kernel<<<(n4 + 255) / 256, 256, 0, stream>>>(x, xh, n4);
  wprep_kernel<<<(Fin * HC1 + 255) / 256, 256, 0, stream>>>(W1, W1th, W1tl, Fin, HC1);

  // ---- layer 1: 2-seg MFMA GEMM (xh@Wh + xh@Wl) + fused alpha ----
  gemm_mfma<64, 256, 1, 4><<<dim3(1, (N + 63) / 64), 256, 0, stream>>>(
      xh, W1th, W1tl, N, Fin, h1b, a_src1, a_dst1, as1, ad1);
  agg4<<<(N + 3) / 4, 256, 0, stream>>>(h1b, as1, ad1, row_ptr, srcs, b1, o1h, N);

  // ---- layer 2: per-node matvec (fp32 W2 in LDS) + fused alpha ----
  const int G2B = 512;
  int rounds = (N + 4 * G2B - 1) / (4 * G2B);
  gemm2_node<<<G2B, 256, 0, stream>>>(o1h, W2, a_src2, a_dst2, h2b, as2, ad2, N, rounds);
  agg1<<<(N + 3) / 4, 256, 0, stream>>>(h2b, as2, ad2, row_ptr, srcs, b2, (float*)d_out, N);
}

// Round 7
// 275.639 us; speedup vs baseline: 1.3371x; 1.3371x over previous
//
#include <hip/hip_runtime.h>

#define LRELU(x) ((x) > 0.f ? (x) : 0.2f * (x))

typedef __attribute__((ext_vector_type(8))) short bf16x8;
typedef __attribute__((ext_vector_type(4))) float f32x4;

__device__ __forceinline__ unsigned short f2bf(float f) {
  unsigned int u = __float_as_uint(f);
  unsigned int r = (u + 0x7fffu + ((u >> 16) & 1u)) >> 16;  // RNE
  return (unsigned short)r;
}
__device__ __forceinline__ float bf2f(unsigned short u) {
  return __uint_as_float(((unsigned int)u) << 16);
}
__device__ __forceinline__ float bflo(unsigned int u) { return __uint_as_float(u << 16); }
__device__ __forceinline__ float bfhi(unsigned int u) { return __uint_as_float(u & 0xffff0000u); }

__device__ __forceinline__ void lgkm0() { asm volatile("s_waitcnt lgkmcnt(0)" ::: "memory"); }

template <int NL>
__device__ __forceinline__ void wait_vmN() {
  if constexpr (NL == 2)      asm volatile("s_waitcnt vmcnt(2)" ::: "memory");
  else if constexpr (NL == 3) asm volatile("s_waitcnt vmcnt(3)" ::: "memory");
  else if constexpr (NL == 5) asm volatile("s_waitcnt vmcnt(5)" ::: "memory");
  else                        asm volatile("s_waitcnt vmcnt(0)" ::: "memory");
}
__device__ __forceinline__ void wait_vm0() { asm volatile("s_waitcnt vmcnt(0)" ::: "memory"); }

#define GLOAD_LDS16(g, l)                                                  \
  __builtin_amdgcn_global_load_lds(                                        \
      (const __attribute__((address_space(1))) void*)(g),                  \
      (__attribute__((address_space(3))) void*)(l), 16, 0, 0)

// ---- edge dtype detection ----
__global__ void detect_i64_kernel(const int* __restrict__ w, int* __restrict__ flag) {
  if (threadIdx.x == 0 && blockIdx.x == 0) {
    int all0 = 1;
    for (int j = 0; j < 128; j++)
      if (w[2 * j + 1] != 0) { all0 = 0; break; }
    *flag = all0;
  }
}
__device__ __forceinline__ int edge_at(const void* ei, long long idx, int is64) {
  if (is64) return (int)((const long long*)ei)[idx];
  return ((const int*)ei)[idx];
}

// ---- CSR build ----
__global__ void hist_kernel(const void* __restrict__ ei, const int* __restrict__ flag,
                            int* __restrict__ counts, int E, int N) {
  int i = blockIdx.x * blockDim.x + threadIdx.x;
  int tot = E + N;
  if (i >= tot) return;
  int f = *flag;
  int d = (i < E) ? edge_at(ei, (long long)E + i, f) : (i - E);
  atomicAdd(&counts[d], 1);
}

__global__ __launch_bounds__(512) void scan1_kernel(const int* __restrict__ counts,
                                                    int* __restrict__ partial,
                                                    int* __restrict__ blocksums, int N) {
  __shared__ int sm[1024];
  int t = threadIdx.x;
  int i = blockIdx.x * 512 + t;
  int v = (i < N) ? counts[i] : 0;
  int* cur = sm; int* nxt = sm + 512;
  cur[t] = v;
  __syncthreads();
  for (int off = 1; off < 512; off <<= 1) {
    int x = cur[t];
    if (t >= off) x += cur[t - off];
    nxt[t] = x;
    __syncthreads();
    int* tmp = cur; cur = nxt; nxt = tmp;
  }
  if (i < N) partial[i] = cur[t];
  if (t == 511) blocksums[blockIdx.x] = cur[511];
}

__global__ __launch_bounds__(512) void scan2_kernel(int* __restrict__ bs, int B) {
  __shared__ int sm[1024];
  int t = threadIdx.x;
  int v = (t < B) ? bs[t] : 0;
  int* cur = sm; int* nxt = sm + 512;
  cur[t] = v;
  __syncthreads();
  for (int off = 1; off < 512; off <<= 1) {
    int x = cur[t];
    if (t >= off) x += cur[t - off];
    nxt[t] = x;
    __syncthreads();
    int* tmp = cur; cur = nxt; nxt = tmp;
  }
  if (t < B) bs[t] = cur[t] - v;
}

__global__ void scan3_kernel(const int* __restrict__ partial, const int* __restrict__ bs,
                             int* __restrict__ row_ptr, int* __restrict__ cursor, int N) {
  int i = blockIdx.x * blockDim.x + threadIdx.x;
  if (i == 0) { row_ptr[0] = 0; cursor[0] = 0; }
  if (i < N) {
    int v = partial[i] + bs[i >> 9];
    row_ptr[i + 1] = v;
    if (i + 1 < N) cursor[i + 1] = v;
  }
}

__global__ void scatter_kernel(const void* __restrict__ ei, const int* __restrict__ flag,
                               int* __restrict__ cursor, int* __restrict__ srcs, int E, int N) {
  int i = blockIdx.x * blockDim.x + threadIdx.x;
  int tot = E + N;
  if (i >= tot) return;
  int f = *flag;
  int s, d;
  if (i < E) {
    s = edge_at(ei, i, f);
    d = edge_at(ei, (long long)E + i, f);
  } else {
    s = i - E; d = s;
  }
  int pos = atomicAdd(&cursor[d], 1);
  srcs[pos] = s;
}

// ---- prep: fp32 -> bf16 (hi only) ----
__global__ __launch_bounds__(256) void tobf16_kernel(const float* __restrict__ x,
                                                     unsigned short* __restrict__ xh, int n4) {
  int i = blockIdx.x * 256 + threadIdx.x;
  if (i >= n4) return;
  float4 v = ((const float4*)x)[i];
  ushort4 h;
  h.x = f2bf(v.x); h.y = f2bf(v.y); h.z = f2bf(v.z); h.w = f2bf(v.w);
  ((ushort4*)xh)[i] = h;
}

// ---- prep: transpose + split W [K][Nc] -> Wt_h/Wt_l [Nc][K] ----
__global__ __launch_bounds__(256) void wprep_kernel(const float* __restrict__ W,
                                                    unsigned short* __restrict__ Wth,
                                                    unsigned short* __restrict__ Wtl,
                                                    int K, int Nc) {
  int idx = blockIdx.x * 256 + threadIdx.x;
  if (idx >= K * Nc) return;
  int n = idx / K, k = idx - n * K;
  float v = W[(size_t)k * Nc + n];
  unsigned short h = f2bf(v);
  Wth[idx] = h;
  Wtl[idx] = f2bf(v - bf2f(h));
}

// ---- MFMA GEMM, 2 segments (A@B0 + A@B1), WM x WN wave grid, dbuf + counted vmcnt ----
// B stored transposed [col][k]. Fused alpha epilogue (wave must cover a full 64-col head).
template <int BROWS, int BCOLS, int WM, int WN, int H>
__global__ __launch_bounds__(256) void gemm_mfma(
    const unsigned short* __restrict__ A0, const unsigned short* __restrict__ B0,
    const unsigned short* __restrict__ B1, int M, int Ka,
    unsigned short* __restrict__ Cb, int ldc, const float* __restrict__ asrc,
    const float* __restrict__ adst, float* __restrict__ as, float* __restrict__ ad) {
  constexpr int WROWS = BROWS / WM;
  constexpr int WCOLS = BCOLS / WN;
  constexpr int MR = WROWS / 16;
  constexpr int NR = WCOLS / 16;
  constexpr int CH_A = BROWS / 64;
  constexpr int CH_B = BCOLS / 64;
  constexpr int NLOADS = CH_A + CH_B;
  __shared__ __align__(16) unsigned short Asm[2][4][BROWS][8];
  __shared__ __align__(16) unsigned short Bsm[2][4][BCOLS][8];
  int tid = threadIdx.x;
  int w = tid >> 6, l = tid & 63;
  int wm = w / WN, wn = w % WN;
  int l16 = l & 15, lg = l >> 4;
  int rowbase = blockIdx.y * BROWS;
  int colbase = blockIdx.x * BCOLS;
  int wrow = wm * WROWS, wcol = wn * WCOLS;
  const int KS = Ka / 32;   // k-steps per segment
  const int NST = 2 * KS;   // total pipeline steps

  auto stage = [&](int buf, int s) {
    int seg = s / KS;
    int kk = (s - seg * KS) * 32;
    const unsigned short* Bp = seg ? B1 : B0;
#pragma unroll
    for (int q = 0; q < CH_A; ++q) {
      int i = q * 256 + tid;
      int p = i / BROWS, r = i % BROWS;
      int gr = rowbase + r;
      if (gr >= M) gr = M - 1;
      const unsigned short* src = A0 + (size_t)gr * Ka + kk + p * 8;
      unsigned short* dst = &Asm[buf][0][0][0] + ((size_t)q * 256 + (tid & ~63)) * 8;
      GLOAD_LDS16(src, dst);
    }
#pragma unroll
    for (int q = 0; q < CH_B; ++q) {
      int i = q * 256 + tid;
      int p = i / BCOLS, r = i % BCOLS;
      const unsigned short* src = Bp + (size_t)(colbase + r) * Ka + kk + p * 8;
      unsigned short* dst = &Bsm[buf][0][0][0] + ((size_t)q * 256 + (tid & ~63)) * 8;
      GLOAD_LDS16(src, dst);
    }
  };

  f32x4 acc[MR][NR] = {};
  stage(0, 0);
  int buf = 0;
  for (int s = 0; s < NST; ++s) {
    if (s + 1 < NST) { stage(buf ^ 1, s + 1); wait_vmN<NLOADS>(); }
    else             { wait_vm0(); }
    __builtin_amdgcn_s_barrier();
    bf16x8 af[MR], bfr[NR];
#pragma unroll
    for (int m = 0; m < MR; ++m) af[m] = *(const bf16x8*)&Asm[buf][lg][wrow + m * 16 + l16][0];
#pragma unroll
    for (int n = 0; n < NR; ++n) bfr[n] = *(const bf16x8*)&Bsm[buf][lg][wcol + n * 16 + l16][0];
#pragma unroll
    for (int m = 0; m < MR; ++m)
#pragma unroll
      for (int n = 0; n < NR; ++n)
        acc[m][n] = __builtin_amdgcn_mfma_f32_16x16x32_bf16(af[m], bfr[n], acc[m][n], 0, 0, 0);
    __builtin_amdgcn_s_barrier();
    buf ^= 1;
  }
  // epilogue: bf16 store
#pragma unroll
  for (int m = 0; m < MR; ++m) {
    int r = rowbase + wrow + m * 16 + lg * 4;
#pragma unroll
    for (int n = 0; n < NR; ++n) {
      int c = colbase + wcol + n * 16 + l16;
#pragma unroll
      for (int j = 0; j < 4; ++j) {
        if (r + j < M) Cb[(size_t)(r + j) * ldc + c] = f2bf(acc[m][n][j]);
      }
    }
  }
  // fused alpha epilogue: wave covers one full head (WCOLS==64) or whole row (H==1)
  float asv[NR], adv_[NR];
#pragma unroll
  for (int n = 0; n < NR; ++n) {
    int c = colbase + wcol + n * 16 + l16;
    asv[n] = asrc[c];
    adv_[n] = adst[c];
  }
  int head = (H == 1) ? 0 : ((colbase + wcol) >> 6);
#pragma unroll
  for (int m = 0; m < MR; ++m) {
#pragma unroll
    for (int j = 0; j < 4; ++j) {
      float ps = 0.f, pd = 0.f;
#pragma unroll
      for (int n = 0; n < NR; ++n) {
        ps = fmaf(acc[m][n][j], asv[n], ps);
        pd = fmaf(acc[m][n][j], adv_[n], pd);
      }
#pragma unroll
      for (int o = 1; o < 16; o <<= 1) { ps += __shfl_xor(ps, o); pd += __shfl_xor(pd, o); }
      int r = rowbase + wrow + m * 16 + lg * 4 + j;
      if (l16 == 0 && r < M) {
        as[(size_t)r * H + head] = ps;
        ad[(size_t)r * H + head] = pd;
      }
    }
  }
}

// ---- layer-1 aggregation: wave per node; lane=(g,p): edge-offset g, 16 channels p ----
__global__ __launch_bounds__(256) void agg4(const unsigned short* __restrict__ hb,
                                            const float* __restrict__ as,
                                            const float* __restrict__ ad,
                                            const int* __restrict__ row_ptr,
                                            const int* __restrict__ srcs,
                                            const float* __restrict__ bias,
                                            unsigned short* __restrict__ oh, int N) {
  __shared__ float els[4][128][4];
  int tid = threadIdx.x;
  int w = tid >> 6, l = tid & 63;
  int gw = (blockIdx.x << 2) + w;
  if (gw >= N) gw = N - 1;
  int g = l >> 4, p = l & 15;
  int beg = row_ptr[gw], end = row_ptr[gw + 1];
  float4 adv = *(const float4*)(ad + (size_t)gw * 4);
  float m0 = -1e30f, m1 = -1e30f, m2 = -1e30f, m3 = -1e30f;
  for (int j = beg + l; j < end; j += 64) {
    int sn = srcs[j];
    float4 a = *(const float4*)(as + (size_t)sn * 4);
    float e0 = LRELU(a.x + adv.x), e1 = LRELU(a.y + adv.y);
    float e2 = LRELU(a.z + adv.z), e3 = LRELU(a.w + adv.w);
    int slot = j - beg;
    if (slot < 128) {
      els[w][slot][0] = e0; els[w][slot][1] = e1;
      els[w][slot][2] = e2; els[w][slot][3] = e3;
    }
    m0 = fmaxf(m0, e0); m1 = fmaxf(m1, e1);
    m2 = fmaxf(m2, e2); m3 = fmaxf(m3, e3);
  }
#pragma unroll
  for (int o = 32; o; o >>= 1) {
    m0 = fmaxf(m0, __shfl_xor(m0, o));
    m1 = fmaxf(m1, __shfl_xor(m1, o));
    m2 = fmaxf(m2, __shfl_xor(m2, o));
    m3 = fmaxf(m3, __shfl_xor(m3, o));
  }
  lgkm0();
  float s0 = 0.f, s1 = 0.f, s2 = 0.f, s3 = 0.f;
  for (int j = beg + l; j < end; j += 64) {
    int slot = j - beg;
    float e0, e1, e2, e3;
    if (slot < 128) {
      e0 = els[w][slot][0]; e1 = els[w][slot][1];
      e2 = els[w][slot][2]; e3 = els[w][slot][3];
    } else {
      int sn = srcs[j];
      float4 a = *(const float4*)(as + (size_t)sn * 4);
      e0 = LRELU(a.x + adv.x); e1 = LRELU(a.y + adv.y);
      e2 = LRELU(a.z + adv.z); e3 = LRELU(a.w + adv.w);
    }
    s0 += __expf(e0 - m0); s1 += __expf(e1 - m1);
    s2 += __expf(e2 - m2); s3 += __expf(e3 - m3);
  }
#pragma unroll
  for (int o = 32; o; o >>= 1) {
    s0 += __shfl_xor(s0, o); s1 += __shfl_xor(s1, o);
    s2 += __shfl_xor(s2, o); s3 += __shfl_xor(s3, o);
  }
  float i0 = 1.f / (s0 + 1e-16f), i1 = 1.f / (s1 + 1e-16f);
  float i2 = 1.f / (s2 + 1e-16f), i3 = 1.f / (s3 + 1e-16f);
  int head = p >> 2;
  float Mh   = head == 0 ? m0 : head == 1 ? m1 : head == 2 ? m2 : m3;
  float Ih   = head == 0 ? i0 : head == 1 ? i1 : head == 2 ? i2 : i3;
  float advh = head == 0 ? adv.x : head == 1 ? adv.y : head == 2 ? adv.z : adv.w;
  float acc[16] = {};
  for (int j0 = beg; j0 < end; j0 += 4) {
    int j = j0 + g;
    if (j < end) {
      int sn = srcs[j];
      int slot = j - beg;
      float e;
      if (slot < 128) {
        e = els[w][slot][head];
      } else {
        float4 a = *(const float4*)(as + (size_t)sn * 4);
        float ah = head == 0 ? a.x : head == 1 ? a.y : head == 2 ? a.z : a.w;
        e = LRELU(ah + advh);
      }
      float al = __expf(e - Mh) * Ih;
      const unsigned short* hp = hb + (size_t)sn * 256 + p * 16;
      uint4 v0 = *(const uint4*)(hp);
      uint4 v1 = *(const uint4*)(hp + 8);
      acc[0]  = fmaf(al, bflo(v0.x), acc[0]);  acc[1]  = fmaf(al, bfhi(v0.x), acc[1]);
      acc[2]  = fmaf(al, bflo(v0.y), acc[2]);  acc[3]  = fmaf(al, bfhi(v0.y), acc[3]);
      acc[4]  = fmaf(al, bflo(v0.z), acc[4]);  acc[5]  = fmaf(al, bfhi(v0.z), acc[5]);
      acc[6]  = fmaf(al, bflo(v0.w), acc[6]);  acc[7]  = fmaf(al, bfhi(v0.w), acc[7]);
      acc[8]  = fmaf(al, bflo(v1.x), acc[8]);  acc[9]  = fmaf(al, bfhi(v1.x), acc[9]);
      acc[10] = fmaf(al, bflo(v1.y), acc[10]); acc[11] = fmaf(al, bfhi(v1.y), acc[11]);
      acc[12] = fmaf(al, bflo(v1.z), acc[12]); acc[13] = fmaf(al, bfhi(v1.z), acc[13]);
      acc[14] = fmaf(al, bflo(v1.w), acc[14]); acc[15] = fmaf(al, bfhi(v1.w), acc[15]);
    }
  }
#pragma unroll
  for (int i = 0; i < 16; ++i) acc[i] += __shfl_xor(acc[i], 16);
#pragma unroll
  for (int i = 0; i < 16; ++i) acc[i] += __shfl_xor(acc[i], 32);
  float o0 = g == 0 ? acc[0] : g == 1 ? acc[4]  : g == 2 ? acc[8]  : acc[12];
  float o1 = g == 0 ? acc[1] : g == 1 ? acc[5]  : g == 2 ? acc[9]  : acc[13];
  float o2 = g == 0 ? acc[2] : g == 1 ? acc[6]  : g == 2 ? acc[10] : acc[14];
  float o3 = g == 0 ? acc[3] : g == 1 ? acc[7]  : g == 2 ? acc[11] : acc[15];
  int c = p * 16 + g * 4;
  ushort4 ov;
  ov.x = f2bf(fmaxf(o0 + bias[c + 0], 0.f));
  ov.y = f2bf(fmaxf(o1 + bias[c + 1], 0.f));
  ov.z = f2bf(fmaxf(o2 + bias[c + 2], 0.f));
  ov.w = f2bf(fmaxf(o3 + bias[c + 3], 0.f));
  *(ushort4*)(oh + (size_t)gw * 256 + c) = ov;
}

// ---- layer-2 aggregation: wave per node; lane=(g,p): edge g, 4 channels p ----
__global__ __launch_bounds__(256) void agg1(const unsigned short* __restrict__ hb,
                                            const float* __restrict__ as,
                                            const float* __restrict__ ad,
                                            const int* __restrict__ row_ptr,
                                            const int* __restrict__ srcs,
                                            const float* __restrict__ bias,
                                            float* __restrict__ out, int N) {
  __shared__ float els[4][128];
  int tid = threadIdx.x;
  int w = tid >> 6, l = tid & 63;
  int gw = (blockIdx.x << 2) + w;
  if (gw >= N) gw = N - 1;
  int g = l >> 4, p = l & 15;
  int beg = row_ptr[gw], end = row_ptr[gw + 1];
  float adn = ad[gw];
  float m = -1e30f;
  for (int j = beg + l; j < end; j += 64) {
    float e = LRELU(as[srcs[j]] + adn);
    int slot = j - beg;
    if (slot < 128) els[w][slot] = e;
    m = fmaxf(m, e);
  }
#pragma unroll
  for (int o = 32; o; o >>= 1) m = fmaxf(m, __shfl_xor(m, o));
  lgkm0();
  float s = 0.f;
  for (int j = beg + l; j < end; j += 64) {
    int slot = j - beg;
    float e = (slot < 128) ? els[w][slot] : LRELU(as[srcs[j]] + adn);
    s += __expf(e - m);
  }
#pragma unroll
  for (int o = 32; o; o >>= 1) s += __shfl_xor(s, o);
  float inv = 1.f / (s + 1e-16f);
  float acc[4] = {};
  for (int j0 = beg; j0 < end; j0 += 4) {
    int j = j0 + g;
    if (j < end) {
      int sn = srcs[j];
      int slot = j - beg;
      float e = (slot < 128) ? els[w][slot] : LRELU(as[sn] + adn);
      float al = __expf(e - m) * inv;
      ushort4 hv = *(const ushort4*)(hb + (size_t)sn * 64 + p * 4);
      acc[0] = fmaf(al, bf2f(hv.x), acc[0]);
      acc[1] = fmaf(al, bf2f(hv.y), acc[1]);
      acc[2] = fmaf(al, bf2f(hv.z), acc[2]);
      acc[3] = fmaf(al, bf2f(hv.w), acc[3]);
    }
  }
#pragma unroll
  for (int i = 0; i < 4; ++i) acc[i] += __shfl_xor(acc[i], 16);
#pragma unroll
  for (int i = 0; i < 4; ++i) acc[i] += __shfl_xor(acc[i], 32);
  float ov = g == 0 ? acc[0] : g == 1 ? acc[1] : g == 2 ? acc[2] : acc[3];
  int c = p * 4 + g;
  out[(size_t)gw * 64 + c] = ov + bias[c];
}

extern "C" void kernel_launch(void* const* d_in, const int* in_sizes, int n_in,
                              void* d_out, int out_size, void* d_ws, size_t ws_size,
                              hipStream_t stream) {
  const float* x      = (const float*)d_in[0];
  const void*  ei     = d_in[1];
  const float* W1     = (const float*)d_in[2];
  const float* a_src1 = (const float*)d_in[3];
  const float* a_dst1 = (const float*)d_in[4];
  const float* b1     = (const float*)d_in[5];
  const float* W2     = (const float*)d_in[6];
  const float* a_src2 = (const float*)d_in[7];
  const float* a_dst2 = (const float*)d_in[8];
  const float* b2     = (const float*)d_in[9];

  const int Fin = 128;
  const int N   = in_sizes[0] / Fin;  // 50000
  const int E   = in_sizes[1] / 2;    // 800000
  const int HC1 = in_sizes[2] / Fin;  // 256
  const int Etot = E + N;

  char* wp = (char*)d_ws;
  auto alloc = [&](size_t bytes) {
    void* p = (void*)wp;
    wp += (bytes + 255) & ~(size_t)255;
    return p;
  };
  int* counts    = (int*)alloc((size_t)N * 4);
  int* row_ptr   = (int*)alloc((size_t)(N + 1) * 4);
  int* cursor    = (int*)alloc((size_t)N * 4);
  int* partial   = (int*)alloc((size_t)N * 4);
  int* blocksums = (int*)alloc(4096);
  int* flag      = (int*)alloc(256);
  int* srcs      = (int*)alloc((size_t)Etot * 4);
  unsigned short* xh   = (unsigned short*)alloc((size_t)N * Fin * 2);   // 12.8MB
  unsigned short* xpad = (unsigned short*)alloc((size_t)N * Fin * 2);   // o1h tail region
  unsigned short* W1th = (unsigned short*)alloc((size_t)HC1 * Fin * 2);
  unsigned short* W1tl = (unsigned short*)alloc((size_t)HC1 * Fin * 2);
  unsigned short* W2th = (unsigned short*)alloc((size_t)64 * HC1 * 2);
  unsigned short* W2tl = (unsigned short*)alloc((size_t)64 * HC1 * 2);
  unsigned short* h1b  = (unsigned short*)alloc((size_t)N * 256 * 2);   // 25.6MB
  float* as1 = (float*)alloc((size_t)N * 4 * 4);
  float* ad1 = (float*)alloc((size_t)N * 4 * 4);
  float* as2 = (float*)alloc((size_t)N * 4);
  float* ad2 = (float*)alloc((size_t)N * 4);
  (void)xpad;
  // aliases (disjoint lifetimes):
  unsigned short* o1h = xh;   // xh dead after gemm1; xh+xpad = 25.6MB contiguous
  unsigned short* h2b = h1b;  // h1b dead after agg4

  const int SB = (N + 511) / 512;

  // ---- CSR build ----
  detect_i64_kernel<<<1, 64, 0, stream>>>((const int*)ei, flag);
  hipMemsetAsync(counts, 0, (size_t)N * 4, stream);
  hist_kernel<<<(Etot + 255) / 256, 256, 0, stream>>>(ei, flag, counts, E, N);
  scan1_kernel<<<SB, 512, 0, stream>>>(counts, partial, blocksums, N);
  scan2_kernel<<<1, 512, 0, stream>>>(blocksums, SB);
  scan3_kernel<<<(N + 255) / 256, 256, 0, stream>>>(partial, blocksums, row_ptr, cursor, N);
  scatter_kernel<<<(Etot + 255) / 256, 256, 0, stream>>>(ei, flag, cursor, srcs, E, N);

  // ---- prep ----
  int n4 = N * Fin / 4;
  tobf16_kernel<<<(n4 + 255) / 256, 256, 0, stream>>>(x, xh, n4);
  wprep_kernel<<<(Fin * HC1 + 255) / 256, 256, 0, stream>>>(W1, W1th, W1tl, Fin, HC1);
  wprep_kernel<<<(HC1 * 64 + 255) / 256, 256, 0, stream>>>(W2, W2th, W2tl, HC1, 64);

  // ---- layer 1: 2-seg MFMA GEMM (xh@Wh + xh@Wl), 64x128 tiles, 2x2 waves ----
  gemm_mfma<64, 128, 2, 2, 4><<<dim3(2, (N + 63) / 64), 256, 0, stream>>>(
      xh, W1th, W1tl, N, Fin, h1b, 256, a_src1, a_dst1, as1, ad1);
  agg4<<<(N + 3) / 4, 256, 0, stream>>>(h1b, as1, ad1, row_ptr, srcs, b1, o1h, N);

  // ---- layer 2: 2-seg MFMA GEMM (o1h@W2h + o1h@W2l), 64x64 tiles, 4x1 waves ----
  gemm_mfma<64, 64, 4, 1, 1><<<dim3(1, (N + 63) / 64), 256, 0, stream>>>(
      o1h, W2th, W2tl, N, HC1, h2b, 64, a_src2, a_dst2, as2, ad2);
  agg1<<<(N + 3) / 4, 256, 0, stream>>>(h2b, as2, ad2, row_ptr, srcs, b2, (float*)d_out, N);
}

// Round 8
// 259.725 us; speedup vs baseline: 1.4190x; 1.0613x over previous
//
#include <hip/hip_runtime.h>

#define LRELU(x) ((x) > 0.f ? (x) : 0.2f * (x))

typedef __attribute__((ext_vector_type(8))) short bf16x8;
typedef __attribute__((ext_vector_type(4))) float f32x4;

__device__ __forceinline__ unsigned short f2bf(float f) {
  unsigned int u = __float_as_uint(f);
  unsigned int r = (u + 0x7fffu + ((u >> 16) & 1u)) >> 16;  // RNE
  return (unsigned short)r;
}
__device__ __forceinline__ float bf2f(unsigned short u) {
  return __uint_as_float(((unsigned int)u) << 16);
}
__device__ __forceinline__ float bflo(unsigned int u) { return __uint_as_float(u << 16); }
__device__ __forceinline__ float bfhi(unsigned int u) { return __uint_as_float(u & 0xffff0000u); }

__device__ __forceinline__ void lgkm0() { asm volatile("s_waitcnt lgkmcnt(0)" ::: "memory"); }

template <int NL>
__device__ __forceinline__ void wait_vmN() {
  if constexpr (NL == 2)      asm volatile("s_waitcnt vmcnt(2)" ::: "memory");
  else if constexpr (NL == 3) asm volatile("s_waitcnt vmcnt(3)" ::: "memory");
  else if constexpr (NL == 4) asm volatile("s_waitcnt vmcnt(4)" ::: "memory");
  else if constexpr (NL == 5) asm volatile("s_waitcnt vmcnt(5)" ::: "memory");
  else                        asm volatile("s_waitcnt vmcnt(0)" ::: "memory");
}
__device__ __forceinline__ void wait_vm0() { asm volatile("s_waitcnt vmcnt(0)" ::: "memory"); }

#define GLOAD_LDS16(g, l)                                                  \
  __builtin_amdgcn_global_load_lds(                                        \
      (const __attribute__((address_space(1))) void*)(g),                  \
      (__attribute__((address_space(3))) void*)(l), 16, 0, 0)

// ---- per-wave edge dtype detection: int64 -> hi-words of first 128 pairs all 0 ----
__device__ __forceinline__ int wave_detect64(const void* ei) {
  const int* w = (const int*)ei;
  int l = threadIdx.x & 63;
  int v = w[2 * l + 1] | w[2 * l + 129];
  return __ballot(v != 0) == 0ull;  // 1 => int64 layout
}
__device__ __forceinline__ int edge_at(const void* ei, long long idx, int is64) {
  if (is64) return (int)((const long long*)ei)[idx];
  return ((const int*)ei)[idx];
}

// ---- fused prep: tobf16(x) | wprep(W1) | wprep(W2) | hist, by block range ----
__global__ __launch_bounds__(256) void prep_all(
    const float* __restrict__ x, unsigned short* __restrict__ xh, int n4,
    const float* __restrict__ W1, unsigned short* __restrict__ W1th,
    unsigned short* __restrict__ W1tl,
    const float* __restrict__ W2, unsigned short* __restrict__ W2th,
    unsigned short* __restrict__ W2tl,
    const void* __restrict__ ei, int* __restrict__ counts, int E, int N,
    int nbX, int nbW1, int nbW2) {
  int b = blockIdx.x;
  int tid = threadIdx.x;
  if (b < nbX) {
    int i = b * 256 + tid;
    if (i < n4) {
      float4 v = ((const float4*)x)[i];
      ushort4 h;
      h.x = f2bf(v.x); h.y = f2bf(v.y); h.z = f2bf(v.z); h.w = f2bf(v.w);
      ((ushort4*)xh)[i] = h;
    }
    return;
  }
  b -= nbX;
  if (b < nbW1) {
    int idx = b * 256 + tid;
    const int K = 128, Nc = 256;
    if (idx < K * Nc) {
      int n = idx / K, k = idx - n * K;
      float v = W1[(size_t)k * Nc + n];
      unsigned short h = f2bf(v);
      W1th[idx] = h;
      W1tl[idx] = f2bf(v - bf2f(h));
    }
    return;
  }
  b -= nbW1;
  if (b < nbW2) {
    int idx = b * 256 + tid;
    const int K = 256, Nc = 64;
    if (idx < K * Nc) {
      int n = idx / K, k = idx - n * K;
      float v = W2[(size_t)k * Nc + n];
      unsigned short h = f2bf(v);
      W2th[idx] = h;
      W2tl[idx] = f2bf(v - bf2f(h));
    }
    return;
  }
  b -= nbW2;
  // hist (detection BEFORE any lane exits)
  int is64 = wave_detect64(ei);
  int i = b * 256 + tid;
  int tot = E + N;
  if (i >= tot) return;
  int d = (i < E) ? edge_at(ei, (long long)E + i, is64) : (i - E);
  atomicAdd(&counts[d], 1);
}

// ---- CSR scan ----
__global__ __launch_bounds__(512) void scan1_kernel(const int* __restrict__ counts,
                                                    int* __restrict__ partial,
                                                    int* __restrict__ blocksums, int N) {
  __shared__ int sm[1024];
  int t = threadIdx.x;
  int i = blockIdx.x * 512 + t;
  int v = (i < N) ? counts[i] : 0;
  int* cur = sm; int* nxt = sm + 512;
  cur[t] = v;
  __syncthreads();
  for (int off = 1; off < 512; off <<= 1) {
    int x = cur[t];
    if (t >= off) x += cur[t - off];
    nxt[t] = x;
    __syncthreads();
    int* tmp = cur; cur = nxt; nxt = tmp;
  }
  if (i < N) partial[i] = cur[t];
  if (t == 511) blocksums[blockIdx.x] = cur[511];
}

__global__ __launch_bounds__(512) void scan2_kernel(int* __restrict__ bs, int B) {
  __shared__ int sm[1024];
  int t = threadIdx.x;
  int v = (t < B) ? bs[t] : 0;
  int* cur = sm; int* nxt = sm + 512;
  cur[t] = v;
  __syncthreads();
  for (int off = 1; off < 512; off <<= 1) {
    int x = cur[t];
    if (t >= off) x += cur[t - off];
    nxt[t] = x;
    __syncthreads();
    int* tmp = cur; cur = nxt; nxt = tmp;
  }
  if (t < B) bs[t] = cur[t] - v;
}

__global__ void scan3_kernel(const int* __restrict__ partial, const int* __restrict__ bs,
                             int* __restrict__ row_ptr, int* __restrict__ cursor, int N) {
  int i = blockIdx.x * blockDim.x + threadIdx.x;
  if (i == 0) { row_ptr[0] = 0; cursor[0] = 0; }
  if (i < N) {
    int v = partial[i] + bs[i >> 9];
    row_ptr[i + 1] = v;
    if (i + 1 < N) cursor[i + 1] = v;
  }
}

__global__ void scatter_kernel(const void* __restrict__ ei,
                               int* __restrict__ cursor, int* __restrict__ srcs, int E, int N) {
  int is64 = wave_detect64(ei);
  int i = blockIdx.x * blockDim.x + threadIdx.x;
  int tot = E + N;
  if (i >= tot) return;
  int s, d;
  if (i < E) {
    s = edge_at(ei, i, is64);
    d = edge_at(ei, (long long)E + i, is64);
  } else {
    s = i - E; d = s;
  }
  int pos = atomicAdd(&cursor[d], 1);
  srcs[pos] = s;
}

// ---- MFMA GEMM, 2 segments (A@B0 + A@B1), WM x WN wave grid, dbuf + counted vmcnt ----
// B stored transposed [col][k]. Fused alpha epilogue (wave covers a full 64-col head).
template <int BROWS, int BCOLS, int WM, int WN, int H>
__global__ __launch_bounds__(256) void gemm_mfma(
    const unsigned short* __restrict__ A0, const unsigned short* __restrict__ B0,
    const unsigned short* __restrict__ B1, int M, int Ka,
    unsigned short* __restrict__ Cb, int ldc, const float* __restrict__ asrc,
    const float* __restrict__ adst, float* __restrict__ as, float* __restrict__ ad) {
  constexpr int WROWS = BROWS / WM;
  constexpr int WCOLS = BCOLS / WN;
  constexpr int MR = WROWS / 16;
  constexpr int NR = WCOLS / 16;
  constexpr int CH_A = BROWS / 64;
  constexpr int CH_B = BCOLS / 64;
  constexpr int NLOADS = CH_A + CH_B;
  __shared__ __align__(16) unsigned short Asm[2][4][BROWS][8];
  __shared__ __align__(16) unsigned short Bsm[2][4][BCOLS][8];
  int tid = threadIdx.x;
  int w = tid >> 6, l = tid & 63;
  int wm = w / WN, wn = w % WN;
  int l16 = l & 15, lg = l >> 4;
  int rowbase = blockIdx.y * BROWS;
  int colbase = blockIdx.x * BCOLS;
  int wrow = wm * WROWS, wcol = wn * WCOLS;
  const int KS = Ka / 32;
  const int NST = 2 * KS;

  auto stage = [&](int buf, int s) {
    int seg = s / KS;
    int kk = (s - seg * KS) * 32;
    const unsigned short* Bp = seg ? B1 : B0;
#pragma unroll
    for (int q = 0; q < CH_A; ++q) {
      int i = q * 256 + tid;
      int p = i / BROWS, r = i % BROWS;
      int gr = rowbase + r;
      if (gr >= M) gr = M - 1;
      const unsigned short* src = A0 + (size_t)gr * Ka + kk + p * 8;
      unsigned short* dst = &Asm[buf][0][0][0] + ((size_t)q * 256 + (tid & ~63)) * 8;
      GLOAD_LDS16(src, dst);
    }
#pragma unroll
    for (int q = 0; q < CH_B; ++q) {
      int i = q * 256 + tid;
      int p = i / BCOLS, r = i % BCOLS;
      const unsigned short* src = Bp + (size_t)(colbase + r) * Ka + kk + p * 8;
      unsigned short* dst = &Bsm[buf][0][0][0] + ((size_t)q * 256 + (tid & ~63)) * 8;
      GLOAD_LDS16(src, dst);
    }
  };

  f32x4 acc[MR][NR] = {};
  stage(0, 0);
  int buf = 0;
  for (int s = 0; s < NST; ++s) {
    if (s + 1 < NST) { stage(buf ^ 1, s + 1); wait_vmN<NLOADS>(); }
    else             { wait_vm0(); }
    __builtin_amdgcn_s_barrier();
    bf16x8 af[MR], bfr[NR];
#pragma unroll
    for (int m = 0; m < MR; ++m) af[m] = *(const bf16x8*)&Asm[buf][lg][wrow + m * 16 + l16][0];
#pragma unroll
    for (int n = 0; n < NR; ++n) bfr[n] = *(const bf16x8*)&Bsm[buf][lg][wcol + n * 16 + l16][0];
#pragma unroll
    for (int m = 0; m < MR; ++m)
#pragma unroll
      for (int n = 0; n < NR; ++n)
        acc[m][n] = __builtin_amdgcn_mfma_f32_16x16x32_bf16(af[m], bfr[n], acc[m][n], 0, 0, 0);
    __builtin_amdgcn_s_barrier();
    buf ^= 1;
  }
#pragma unroll
  for (int m = 0; m < MR; ++m) {
    int r = rowbase + wrow + m * 16 + lg * 4;
#pragma unroll
    for (int n = 0; n < NR; ++n) {
      int c = colbase + wcol + n * 16 + l16;
#pragma unroll
      for (int j = 0; j < 4; ++j) {
        if (r + j < M) Cb[(size_t)(r + j) * ldc + c] = f2bf(acc[m][n][j]);
      }
    }
  }
  float asv[NR], adv_[NR];
#pragma unroll
  for (int n = 0; n < NR; ++n) {
    int c = colbase + wcol + n * 16 + l16;
    asv[n] = asrc[c];
    adv_[n] = adst[c];
  }
  int head = (H == 1) ? 0 : ((colbase + wcol) >> 6);
#pragma unroll
  for (int m = 0; m < MR; ++m) {
#pragma unroll
    for (int j = 0; j < 4; ++j) {
      float ps = 0.f, pd = 0.f;
#pragma unroll
      for (int n = 0; n < NR; ++n) {
        ps = fmaf(acc[m][n][j], asv[n], ps);
        pd = fmaf(acc[m][n][j], adv_[n], pd);
      }
#pragma unroll
      for (int o = 1; o < 16; o <<= 1) { ps += __shfl_xor(ps, o); pd += __shfl_xor(pd, o); }
      int r = rowbase + wrow + m * 16 + lg * 4 + j;
      if (l16 == 0 && r < M) {
        as[(size_t)r * H + head] = ps;
        ad[(size_t)r * H + head] = pd;
      }
    }
  }
}

// ---- layer-1 aggregation: wave per node; lane=(g,p): edge-offset g in [0,4), 16 ch p ----
__global__ __launch_bounds__(256) void agg4(const unsigned short* __restrict__ hb,
                                            const float* __restrict__ as,
                                            const float* __restrict__ ad,
                                            const int* __restrict__ row_ptr,
                                            const int* __restrict__ srcs,
                                            const float* __restrict__ bias,
                                            unsigned short* __restrict__ oh, int N) {
  __shared__ float els[4][128][4];
  int tid = threadIdx.x;
  int w = tid >> 6, l = tid & 63;
  int gw = (blockIdx.x << 2) + w;
  if (gw >= N) gw = N - 1;
  int g = l >> 4, p = l & 15;
  int beg = row_ptr[gw], end = row_ptr[gw + 1];
  float4 adv = *(const float4*)(ad + (size_t)gw * 4);
  float m0 = -1e30f, m1 = -1e30f, m2 = -1e30f, m3 = -1e30f;
  for (int j = beg + l; j < end; j += 64) {
    int sn = srcs[j];
    float4 a = *(const float4*)(as + (size_t)sn * 4);
    float e0 = LRELU(a.x + adv.x), e1 = LRELU(a.y + adv.y);
    float e2 = LRELU(a.z + adv.z), e3 = LRELU(a.w + adv.w);
    int slot = j - beg;
    if (slot < 128) {
      els[w][slot][0] = e0; els[w][slot][1] = e1;
      els[w][slot][2] = e2; els[w][slot][3] = e3;
    }
    m0 = fmaxf(m0, e0); m1 = fmaxf(m1, e1);
    m2 = fmaxf(m2, e2); m3 = fmaxf(m3, e3);
  }
#pragma unroll
  for (int o = 32; o; o >>= 1) {
    m0 = fmaxf(m0, __shfl_xor(m0, o));
    m1 = fmaxf(m1, __shfl_xor(m1, o));
    m2 = fmaxf(m2, __shfl_xor(m2, o));
    m3 = fmaxf(m3, __shfl_xor(m3, o));
  }
  lgkm0();
  float s0 = 0.f, s1 = 0.f, s2 = 0.f, s3 = 0.f;
  for (int j = beg + l; j < end; j += 64) {
    int slot = j - beg;
    float e0, e1, e2, e3;
    if (slot < 128) {
      e0 = els[w][slot][0]; e1 = els[w][slot][1];
      e2 = els[w][slot][2]; e3 = els[w][slot][3];
    } else {
      int sn = srcs[j];
      float4 a = *(const float4*)(as + (size_t)sn * 4);
      e0 = LRELU(a.x + adv.x); e1 = LRELU(a.y + adv.y);
      e2 = LRELU(a.z + adv.z); e3 = LRELU(a.w + adv.w);
    }
    s0 += __expf(e0 - m0); s1 += __expf(e1 - m1);
    s2 += __expf(e2 - m2); s3 += __expf(e3 - m3);
  }
#pragma unroll
  for (int o = 32; o; o >>= 1) {
    s0 += __shfl_xor(s0, o); s1 += __shfl_xor(s1, o);
    s2 += __shfl_xor(s2, o); s3 += __shfl_xor(s3, o);
  }
  float i0 = 1.f / (s0 + 1e-16f), i1 = 1.f / (s1 + 1e-16f);
  float i2 = 1.f / (s2 + 1e-16f), i3 = 1.f / (s3 + 1e-16f);
  int head = p >> 2;
  float Mh   = head == 0 ? m0 : head == 1 ? m1 : head == 2 ? m2 : m3;
  float Ih   = head == 0 ? i0 : head == 1 ? i1 : head == 2 ? i2 : i3;
  float advh = head == 0 ? adv.x : head == 1 ? adv.y : head == 2 ? adv.z : adv.w;
  // phase 3 with 2-deep software pipeline
  float acc[16] = {};
  int j = beg + g;
  bool have = j < end;
  float e_c = 0.f; uint4 v0_c = {}, v1_c = {};
  if (have) {
    int sn = srcs[j];
    int slot = j - beg;
    if (slot < 128) e_c = els[w][slot][head];
    else {
      float4 a = *(const float4*)(as + (size_t)sn * 4);
      float ah = head == 0 ? a.x : head == 1 ? a.y : head == 2 ? a.z : a.w;
      e_c = LRELU(ah + advh);
    }
    const unsigned short* hp = hb + (size_t)sn * 256 + p * 16;
    v0_c = *(const uint4*)(hp);
    v1_c = *(const uint4*)(hp + 8);
  }
  while (have) {
    int jn = j + 4;
    bool have_n = jn < end;
    float e_n = 0.f; uint4 v0_n = {}, v1_n = {};
    if (have_n) {
      int sn = srcs[jn];
      int slot = jn - beg;
      if (slot < 128) e_n = els[w][slot][head];
      else {
        float4 a = *(const float4*)(as + (size_t)sn * 4);
        float ah = head == 0 ? a.x : head == 1 ? a.y : head == 2 ? a.z : a.w;
        e_n = LRELU(ah + advh);
      }
      const unsigned short* hp = hb + (size_t)sn * 256 + p * 16;
      v0_n = *(const uint4*)(hp);
      v1_n = *(const uint4*)(hp + 8);
    }
    float al = __expf(e_c - Mh) * Ih;
    acc[0]  = fmaf(al, bflo(v0_c.x), acc[0]);  acc[1]  = fmaf(al, bfhi(v0_c.x), acc[1]);
    acc[2]  = fmaf(al, bflo(v0_c.y), acc[2]);  acc[3]  = fmaf(al, bfhi(v0_c.y), acc[3]);
    acc[4]  = fmaf(al, bflo(v0_c.z), acc[4]);  acc[5]  = fmaf(al, bfhi(v0_c.z), acc[5]);
    acc[6]  = fmaf(al, bflo(v0_c.w), acc[6]);  acc[7]  = fmaf(al, bfhi(v0_c.w), acc[7]);
    acc[8]  = fmaf(al, bflo(v1_c.x), acc[8]);  acc[9]  = fmaf(al, bfhi(v1_c.x), acc[9]);
    acc[10] = fmaf(al, bflo(v1_c.y), acc[10]); acc[11] = fmaf(al, bfhi(v1_c.y), acc[11]);
    acc[12] = fmaf(al, bflo(v1_c.z), acc[12]); acc[13] = fmaf(al, bfhi(v1_c.z), acc[13]);
    acc[14] = fmaf(al, bflo(v1_c.w), acc[14]); acc[15] = fmaf(al, bfhi(v1_c.w), acc[15]);
    j = jn; have = have_n; e_c = e_n; v0_c = v0_n; v1_c = v1_n;
  }
#pragma unroll
  for (int i = 0; i < 16; ++i) acc[i] += __shfl_xor(acc[i], 16);
#pragma unroll
  for (int i = 0; i < 16; ++i) acc[i] += __shfl_xor(acc[i], 32);
  float o0 = g == 0 ? acc[0] : g == 1 ? acc[4]  : g == 2 ? acc[8]  : acc[12];
  float o1 = g == 0 ? acc[1] : g == 1 ? acc[5]  : g == 2 ? acc[9]  : acc[13];
  float o2 = g == 0 ? acc[2] : g == 1 ? acc[6]  : g == 2 ? acc[10] : acc[14];
  float o3 = g == 0 ? acc[3] : g == 1 ? acc[7]  : g == 2 ? acc[11] : acc[15];
  int c = p * 16 + g * 4;
  ushort4 ov;
  ov.x = f2bf(fmaxf(o0 + bias[c + 0], 0.f));
  ov.y = f2bf(fmaxf(o1 + bias[c + 1], 0.f));
  ov.z = f2bf(fmaxf(o2 + bias[c + 2], 0.f));
  ov.w = f2bf(fmaxf(o3 + bias[c + 3], 0.f));
  *(ushort4*)(oh + (size_t)gw * 256 + c) = ov;
}

// ---- layer-2 aggregation: wave per node; lane=(g,p): edge g in [0,8), 8 ch p ----
__global__ __launch_bounds__(256) void agg1(const unsigned short* __restrict__ hb,
                                            const float* __restrict__ as,
                                            const float* __restrict__ ad,
                                            const int* __restrict__ row_ptr,
                                            const int* __restrict__ srcs,
                                            const float* __restrict__ bias,
                                            float* __restrict__ out, int N) {
  __shared__ float els[4][128];
  int tid = threadIdx.x;
  int w = tid >> 6, l = tid & 63;
  int gw = (blockIdx.x << 2) + w;
  if (gw >= N) gw = N - 1;
  int g = l >> 3, p = l & 7;
  int beg = row_ptr[gw], end = row_ptr[gw + 1];
  float adn = ad[gw];
  float m = -1e30f;
  for (int j = beg + l; j < end; j += 64) {
    float e = LRELU(as[srcs[j]] + adn);
    int slot = j - beg;
    if (slot < 128) els[w][slot] = e;
    m = fmaxf(m, e);
  }
#pragma unroll
  for (int o = 32; o; o >>= 1) m = fmaxf(m, __shfl_xor(m, o));
  lgkm0();
  float s = 0.f;
  for (int j = beg + l; j < end; j += 64) {
    int slot = j - beg;
    float e = (slot < 128) ? els[w][slot] : LRELU(as[srcs[j]] + adn);
    s += __expf(e - m);
  }
#pragma unroll
  for (int o = 32; o; o >>= 1) s += __shfl_xor(s, o);
  float inv = 1.f / (s + 1e-16f);
  // accumulate: 8 edge-groups, lane owns 8 channels [p*8, p*8+8); 2-deep pipeline
  float acc[8] = {};
  int j = beg + g;
  bool have = j < end;
  float e_c = 0.f; uint4 v_c = {};
  if (have) {
    int sn = srcs[j];
    int slot = j - beg;
    e_c = (slot < 128) ? els[w][slot] : LRELU(as[sn] + adn);
    v_c = *(const uint4*)(hb + (size_t)sn * 64 + p * 8);
  }
  while (have) {
    int jn = j + 8;
    bool have_n = jn < end;
    float e_n = 0.f; uint4 v_n = {};
    if (have_n) {
      int sn = srcs[jn];
      int slot = jn - beg;
      e_n = (slot < 128) ? els[w][slot] : LRELU(as[sn] + adn);
      v_n = *(const uint4*)(hb + (size_t)sn * 64 + p * 8);
    }
    float al = __expf(e_c - m) * inv;
    acc[0] = fmaf(al, bflo(v_c.x), acc[0]); acc[1] = fmaf(al, bfhi(v_c.x), acc[1]);
    acc[2] = fmaf(al, bflo(v_c.y), acc[2]); acc[3] = fmaf(al, bfhi(v_c.y), acc[3]);
    acc[4] = fmaf(al, bflo(v_c.z), acc[4]); acc[5] = fmaf(al, bfhi(v_c.z), acc[5]);
    acc[6] = fmaf(al, bflo(v_c.w), acc[6]); acc[7] = fmaf(al, bfhi(v_c.w), acc[7]);
    j = jn; have = have_n; e_c = e_n; v_c = v_n;
  }
#pragma unroll
  for (int i = 0; i < 8; ++i) acc[i] += __shfl_xor(acc[i], 8);
#pragma unroll
  for (int i = 0; i < 8; ++i) acc[i] += __shfl_xor(acc[i], 16);
#pragma unroll
  for (int i = 0; i < 8; ++i) acc[i] += __shfl_xor(acc[i], 32);
  float ov = g == 0 ? acc[0] : g == 1 ? acc[1] : g == 2 ? acc[2] : g == 3 ? acc[3]
           : g == 4 ? acc[4] : g == 5 ? acc[5] : g == 6 ? acc[6] : acc[7];
  int c = p * 8 + g;
  out[(size_t)gw * 64 + c] = ov + bias[c];
}

extern "C" void kernel_launch(void* const* d_in, const int* in_sizes, int n_in,
                              void* d_out, int out_size, void* d_ws, size_t ws_size,
                              hipStream_t stream) {
  const float* x      = (const float*)d_in[0];
  const void*  ei     = d_in[1];
  const float* W1     = (const float*)d_in[2];
  const float* a_src1 = (const float*)d_in[3];
  const float* a_dst1 = (const float*)d_in[4];
  const float* b1     = (const float*)d_in[5];
  const float* W2     = (const float*)d_in[6];
  const float* a_src2 = (const float*)d_in[7];
  const float* a_dst2 = (const float*)d_in[8];
  const float* b2     = (const float*)d_in[9];

  const int Fin = 128;
  const int N   = in_sizes[0] / Fin;  // 50000
  const int E   = in_sizes[1] / 2;    // 800000
  const int HC1 = in_sizes[2] / Fin;  // 256
  const int Etot = E + N;

  char* wp = (char*)d_ws;
  auto alloc = [&](size_t bytes) {
    void* p = (void*)wp;
    wp += (bytes + 255) & ~(size_t)255;
    return p;
  };
  int* counts    = (int*)alloc((size_t)N * 4);
  int* row_ptr   = (int*)alloc((size_t)(N + 1) * 4);
  int* cursor    = (int*)alloc((size_t)N * 4);
  int* partial   = (int*)alloc((size_t)N * 4);
  int* blocksums = (int*)alloc(4096);
  int* srcs      = (int*)alloc((size_t)Etot * 4);
  unsigned short* xh   = (unsigned short*)alloc((size_t)N * Fin * 2);   // 12.8MB
  unsigned short* xpad = (unsigned short*)alloc((size_t)N * Fin * 2);   // o1h tail region
  unsigned short* W1th = (unsigned short*)alloc((size_t)HC1 * Fin * 2);
  unsigned short* W1tl = (unsigned short*)alloc((size_t)HC1 * Fin * 2);
  unsigned short* W2th = (unsigned short*)alloc((size_t)64 * HC1 * 2);
  unsigned short* W2tl = (unsigned short*)alloc((size_t)64 * HC1 * 2);
  unsigned short* h1b  = (unsigned short*)alloc((size_t)N * 256 * 2);   // 25.6MB
  float* as1 = (float*)alloc((size_t)N * 4 * 4);
  float* ad1 = (float*)alloc((size_t)N * 4 * 4);
  float* as2 = (float*)alloc((size_t)N * 4);
  float* ad2 = (float*)alloc((size_t)N * 4);
  (void)xpad;
  unsigned short* o1h = xh;   // xh dead after gemm1; xh+xpad = 25.6MB contiguous
  unsigned short* h2b = h1b;  // h1b dead after agg4

  const int SB = (N + 511) / 512;
  const int n4 = N * Fin / 4;
  const int nbX  = (n4 + 255) / 256;
  const int nbW1 = (Fin * HC1 + 255) / 256;
  const int nbW2 = (HC1 * 64 + 255) / 256;
  const int nbH  = (Etot + 255) / 256;

  // ---- fused prep (tobf16 | wprep1 | wprep2 | hist) ----
  hipMemsetAsync(counts, 0, (size_t)N * 4, stream);
  prep_all<<<nbX + nbW1 + nbW2 + nbH, 256, 0, stream>>>(
      x, xh, n4, W1, W1th, W1tl, W2, W2th, W2tl, ei, counts, E, N, nbX, nbW1, nbW2);

  // ---- CSR scan + scatter ----
  scan1_kernel<<<SB, 512, 0, stream>>>(counts, partial, blocksums, N);
  scan2_kernel<<<1, 512, 0, stream>>>(blocksums, SB);
  scan3_kernel<<<(N + 255) / 256, 256, 0, stream>>>(partial, blocksums, row_ptr, cursor, N);
  scatter_kernel<<<(Etot + 255) / 256, 256, 0, stream>>>(ei, cursor, srcs, E, N);

  // ---- layer 1: 2-seg MFMA GEMM (xh@Wh + xh@Wl), 128x128 tiles, 2x2 waves ----
  gemm_mfma<128, 128, 2, 2, 4><<<dim3(2, (N + 127) / 128), 256, 0, stream>>>(
      xh, W1th, W1tl, N, Fin, h1b, 256, a_src1, a_dst1, as1, ad1);
  agg4<<<(N + 3) / 4, 256, 0, stream>>>(h1b, as1, ad1, row_ptr, srcs, b1, o1h, N);

  // ---- layer 2: 2-seg MFMA GEMM (o1h@W2h + o1h@W2l), 64x64 tiles, 4x1 waves ----
  gemm_mfma<64, 64, 4, 1, 1><<<dim3(1, (N + 63) / 64), 256, 0, stream>>>(
      o1h, W2th, W2tl, N, HC1, h2b, 64, a_src2, a_dst2, as2, ad2);
  agg1<<<(N + 3) / 4, 256, 0, stream>>>(h2b, as2, ad2, row_ptr, srcs, b2, (float*)d_out, N);
}